// Round 1
// baseline (47.818 us; speedup 1.0000x reference)
//
#include <hip/hip_runtime.h>

// Problem constants (from reference): prediction [10,5,10,1024,100] f32, label [1024] int.
constexpr int C = 100;        // classes
constexpr int B = 1024;       // batch
constexpr int NROWS = 10 * 5 * 10 * 1024;  // 512000 rows of C floats
constexpr float MT_SUM = 0.6f;   // m + T = 0.1 + 0.5
constexpr float M_MARGIN = 0.1f;

__global__ __launch_bounds__(256) void loss_rows_kernel(
    const float* __restrict__ pred,
    const int* __restrict__ lab,
    float* __restrict__ partial)
{
    const int r = blockIdx.x * 256 + threadIdx.x;
    float l = 0.0f;
    if (r < NROWS) {
        const int y = lab[r & (B - 1)];   // b = row % 1024 (B is innermost-but-one dim)
        const float4* row = reinterpret_cast<const float4*>(pred + (size_t)r * C);
        float fy = 0.0f;
        float mx = -1e30f;
#pragma unroll
        for (int k = 0; k < 25; ++k) {
            const float4 v = row[k];
            const int c0 = 4 * k;
            fy = (c0 + 0 == y) ? v.x : fy;
            mx = fmaxf(mx, (c0 + 0 == y) ? -1e30f : v.x);
            fy = (c0 + 1 == y) ? v.y : fy;
            mx = fmaxf(mx, (c0 + 1 == y) ? -1e30f : v.y);
            fy = (c0 + 2 == y) ? v.z : fy;
            mx = fmaxf(mx, (c0 + 2 == y) ? -1e30f : v.z);
            fy = (c0 + 3 == y) ? v.w : fy;
            mx = fmaxf(mx, (c0 + 3 == y) ? -1e30f : v.w);
        }
        l = fmaxf(MT_SUM - fy, 0.0f) + fmaxf(M_MARGIN + mx, 0.0f);
    }
    // wave (64-lane) reduction
#pragma unroll
    for (int off = 32; off > 0; off >>= 1)
        l += __shfl_down(l, off, 64);
    __shared__ float ws[4];
    const int wave = threadIdx.x >> 6;
    const int lane = threadIdx.x & 63;
    if (lane == 0) ws[wave] = l;
    __syncthreads();
    if (threadIdx.x == 0)
        partial[blockIdx.x] = ws[0] + ws[1] + ws[2] + ws[3];
}

__global__ __launch_bounds__(256) void reduce_final_kernel(
    const float* __restrict__ partial, int n, float* __restrict__ out)
{
    float s = 0.0f;
    for (int i = threadIdx.x; i < n; i += 256) s += partial[i];
#pragma unroll
    for (int off = 32; off > 0; off >>= 1)
        s += __shfl_down(s, off, 64);
    __shared__ float ws[4];
    const int wave = threadIdx.x >> 6;
    const int lane = threadIdx.x & 63;
    if (lane == 0) ws[wave] = s;
    __syncthreads();
    if (threadIdx.x == 0)
        out[0] = (ws[0] + ws[1] + ws[2] + ws[3]) * (1.0f / (float)NROWS);
}

extern "C" void kernel_launch(void* const* d_in, const int* in_sizes, int n_in,
                              void* d_out, int out_size, void* d_ws, size_t ws_size,
                              hipStream_t stream) {
    const float* pred = (const float*)d_in[0];
    const int* lab = (const int*)d_in[1];
    float* out = (float*)d_out;
    float* partial = (float*)d_ws;

    const int nblocks = (NROWS + 255) / 256;  // 2000
    loss_rows_kernel<<<nblocks, 256, 0, stream>>>(pred, lab, partial);
    reduce_final_kernel<<<1, 256, 0, stream>>>(partial, nblocks, out);
}

// Round 2
// 36.410 us; speedup vs baseline: 1.3133x; 1.3133x over previous
//
#include <hip/hip_runtime.h>

// prediction [10,5,10,1024,100] f32, label [1024] int.
constexpr int C = 100;
constexpr int B = 1024;
constexpr int NROWS = 10 * 5 * 10 * 1024;     // 512000 rows of C floats
constexpr float MT_SUM = 0.6f;                // m + T
constexpr float M_MARGIN = 0.1f;
constexpr int ROWS_PER_BLOCK = 64;            // 256 threads / 4 lanes-per-row
constexpr int NBLOCKS = NROWS / ROWS_PER_BLOCK;  // 8000, divides exactly

__global__ __launch_bounds__(256) void loss_rows_kernel(
    const float* __restrict__ pred,
    const int* __restrict__ lab,
    float* __restrict__ partial)
{
    const int t = threadIdx.x;
    const int g = t & 3;          // lane within 4-lane row group
    const int r = blockIdx.x * ROWS_PER_BLOCK + (t >> 2);
    const int y = lab[r & (B - 1)];

    const float4* row = reinterpret_cast<const float4*>(pred + (size_t)r * C);
    float fy = -1e30f;            // sentinel; exactly one lane in group finds y
    float mx = -1e30f;
#pragma unroll
    for (int k = 0; k < 7; ++k) {
        const int fi = g + 4 * k; // float4 index within row; lanes cover 64B contiguous
        if (fi < 25) {
            const float4 v = row[fi];
            const int c0 = 4 * fi;
            const bool e0 = (c0 + 0 == y), e1 = (c0 + 1 == y),
                       e2 = (c0 + 2 == y), e3 = (c0 + 3 == y);
            fy = e0 ? v.x : fy;  mx = fmaxf(mx, e0 ? -1e30f : v.x);
            fy = e1 ? v.y : fy;  mx = fmaxf(mx, e1 ? -1e30f : v.y);
            fy = e2 ? v.z : fy;  mx = fmaxf(mx, e2 ? -1e30f : v.z);
            fy = e3 ? v.w : fy;  mx = fmaxf(mx, e3 ? -1e30f : v.w);
        }
    }
    // reduce fy / mx across the aligned 4-lane group
    fy = fmaxf(fy, __shfl_xor(fy, 1, 64));
    fy = fmaxf(fy, __shfl_xor(fy, 2, 64));
    mx = fmaxf(mx, __shfl_xor(mx, 1, 64));
    mx = fmaxf(mx, __shfl_xor(mx, 2, 64));

    float l = fmaxf(MT_SUM - fy, 0.0f) + fmaxf(M_MARGIN + mx, 0.0f);
    // each row is computed by 4 lanes -> weight 0.25

    // wave (64-lane) sum reduction
#pragma unroll
    for (int off = 32; off > 0; off >>= 1)
        l += __shfl_down(l, off, 64);
    __shared__ float ws[4];
    const int wave = t >> 6;
    const int lane = t & 63;
    if (lane == 0) ws[wave] = l;
    __syncthreads();
    if (t == 0)
        partial[blockIdx.x] = (ws[0] + ws[1] + ws[2] + ws[3]) * 0.25f;
}

__global__ __launch_bounds__(1024) void reduce_final_kernel(
    const float* __restrict__ partial, int n, float* __restrict__ out)
{
    float s = 0.0f;
    for (int i = threadIdx.x; i < n; i += 1024) s += partial[i];
#pragma unroll
    for (int off = 32; off > 0; off >>= 1)
        s += __shfl_down(s, off, 64);
    __shared__ float ws[16];
    const int wave = threadIdx.x >> 6;
    const int lane = threadIdx.x & 63;
    if (lane == 0) ws[wave] = s;
    __syncthreads();
    if (threadIdx.x == 0) {
        float tot = 0.0f;
#pragma unroll
        for (int w = 0; w < 16; ++w) tot += ws[w];
        out[0] = tot * (1.0f / (float)NROWS);
    }
}

extern "C" void kernel_launch(void* const* d_in, const int* in_sizes, int n_in,
                              void* d_out, int out_size, void* d_ws, size_t ws_size,
                              hipStream_t stream) {
    const float* pred = (const float*)d_in[0];
    const int* lab = (const int*)d_in[1];
    float* out = (float*)d_out;
    float* partial = (float*)d_ws;

    loss_rows_kernel<<<NBLOCKS, 256, 0, stream>>>(pred, lab, partial);
    reduce_final_kernel<<<1, 1024, 0, stream>>>(partial, NBLOCKS, out);
}